// Round 3
// baseline (143.790 us; speedup 1.0000x reference)
//
#include <hip/hip_runtime.h>
#include <hip/hip_cooperative_groups.h>
#include <stdint.h>

namespace cg = cooperative_groups;

// Problem constants (from reference)
#define N_NODES 10000
#define N_FEATS 128
#define BSZ 32
#define D_ELEMS 100000

#define OUT_ELEMS (BSZ * N_NODES * N_FEATS)   // 40,960,000 floats
#define N_ITEMS   (BSZ * D_ELEMS)             // 3,200,000
#define N_GROUPS  (N_ITEMS / 4)               // 800,000 x4-groups

#define NBUCKET 512
#define CHUNK   (OUT_ELEMS / NBUCKET)         // 80,000 floats per bucket (exact)
#define CAP     8064                          // mean 6250, +23 sigma; 33.03 MB total
#define SUBF    8000                          // floats per LDS half (32 KB); double-buffered
#define NSUB    (CHUNK / SUBF)                // 10 (exact)

// Fused geometry: 512 blocks x 1024 threads (== expand geometry).
#define FGPB  ((N_GROUPS + NBUCKET - 1) / NBUCKET)   // 1563 groups per fused block
#define SP_N  6272                                   // staged pairs capacity (>= 4*1563)

// Fallback bin geometry (round-2 proven): 782 blocks x 512 threads.
#define BIN_GPB   1024
#define BIN_NBLK  ((N_GROUPS + BIN_GPB - 1) / BIN_GPB)  // 782

typedef float f32x4 __attribute__((ext_vector_type(4)));
typedef int   i32x4 __attribute__((ext_vector_type(4)));

// ===================== Fused cooperative kernel =====================
// Phase A (bin): block-local bucket sort of 1563 groups, run-coalesced flush
//   into pairs[bucket*CAP + atomic base]. gcount zeroed in-kernel (block b
//   zeroes bucket b), ordered against the atomics by grid.sync.
// Phase B (expand): bucket b's dense replay, double-buffered LDS halves so
//   scatter(p+1) overlaps dump+rezero(p); one barrier per sub-pass.
__global__ __launch_bounds__(1024, 2) void fused_kernel(
    const f32x4* __restrict__ vals,
    const i32x4* __restrict__ nodes,
    const i32x4* __restrict__ feats,
    uint64_t* __restrict__ pairs,      // [NBUCKET][CAP]
    uint32_t* __restrict__ gcount,     // [NBUCKET]
    float* __restrict__ out) {
  __shared__ alignas(16) uint8_t smem[64512];
  uint64_t* sp     = (uint64_t*)smem;               // [SP_N]   50,176 B
  uint32_t* hist   = (uint32_t*)(smem + 50176);     // [512]
  uint32_t* excl   = (uint32_t*)(smem + 52224);     // [512]
  uint32_t* base_s = (uint32_t*)(smem + 54272);     // [512]
  uint32_t* wpart  = (uint32_t*)(smem + 56320);     // [16]
  uint32_t* tot_p  = (uint32_t*)(smem + 56384);

  cg::grid_group grid = cg::this_grid();
  const int tid = threadIdx.x;
  const int blk = blockIdx.x;

  // ---- zero my bucket's counter (ordered vs atomics by grid.sync #1) ----
  if (tid == 0) gcount[blk] = 0u;
  if (tid < NBUCKET) hist[tid] = 0u;
  __syncthreads();

  // ---- load up to 2 groups / thread (1563 groups per block) ----
  uint32_t lin[8]; float val[8]; uint32_t rnk[8];
  const int gbase = blk * FGPB;
#pragma unroll
  for (int q = 0; q < 2; ++q) {
    int sub = q * 1024 + tid;
    int g = gbase + sub;
    bool a = (sub < FGPB) && (g < N_GROUPS);
    int gg = a ? g : 0;
    f32x4 v = vals[gg];
    i32x4 n = nodes[gg];
    i32x4 f = feats[gg];
    uint32_t rowbase = (uint32_t)((gg * 4) / D_ELEMS) * (uint32_t)(N_NODES * N_FEATS);
    lin[q*4+0] = a ? rowbase + (uint32_t)n.x * N_FEATS + (uint32_t)f.x : 0xFFFFFFFFu;
    lin[q*4+1] = a ? rowbase + (uint32_t)n.y * N_FEATS + (uint32_t)f.y : 0xFFFFFFFFu;
    lin[q*4+2] = a ? rowbase + (uint32_t)n.z * N_FEATS + (uint32_t)f.z : 0xFFFFFFFFu;
    lin[q*4+3] = a ? rowbase + (uint32_t)n.w * N_FEATS + (uint32_t)f.w : 0xFFFFFFFFu;
    val[q*4+0] = v.x; val[q*4+1] = v.y; val[q*4+2] = v.z; val[q*4+3] = v.w;
  }

#pragma unroll
  for (int i = 0; i < 8; ++i)
    if (lin[i] != 0xFFFFFFFFu)
      rnk[i] = atomicAdd(&hist[lin[i] / CHUNK], 1u);
  __syncthreads();

  // ---- exclusive scan of hist[512] (waves 0..7 shuffle-scan + partials) ----
  uint32_t h = 0, v = 0;
  if (tid < NBUCKET) {
    h = hist[tid];
    v = h;
#pragma unroll
    for (int s = 1; s < 64; s <<= 1) {
      uint32_t u = __shfl_up(v, s, 64);
      if ((tid & 63) >= s) v += u;
    }
    if ((tid & 63) == 63) wpart[tid >> 6] = v;
  }
  __syncthreads();
  if (tid < 64) {
    uint32_t p = (tid < 8) ? wpart[tid] : 0u;
#pragma unroll
    for (int s = 1; s < 8; s <<= 1) {
      uint32_t u = __shfl_up(p, s, 64);
      if (tid >= s) p += u;
    }
    if (tid < 8) wpart[tid] = p;     // inclusive partial sums
  }
  __syncthreads();
  if (tid < NBUCKET) {
    uint32_t woff = (tid >= 64) ? wpart[(tid >> 6) - 1] : 0u;
    uint32_t incl = v + woff;
    excl[tid] = incl - h;
    if (tid == NBUCKET - 1) *tot_p = incl;
  }
  __syncthreads();

  // ---- stage pairs bucket-sorted in LDS ----
#pragma unroll
  for (int i = 0; i < 8; ++i) {
    if (lin[i] != 0xFFFFFFFFu) {
      uint32_t b = lin[i] / CHUNK;
      sp[excl[b] + rnk[i]] =
          ((uint64_t)__float_as_uint(val[i]) << 32) | (uint64_t)lin[i];
    }
  }
  const uint32_t tot = *tot_p;

  grid.sync();   // #1: all gcount zeroes done; all blocks staged

  // ---- per-bucket global bases, then run-coalesced flush ----
  if (tid < NBUCKET)
    base_s[tid] = h ? atomicAdd(&gcount[tid], h) : 0u;
  __syncthreads();
  for (uint32_t i = tid; i < tot; i += 1024u) {
    uint64_t p = sp[i];
    uint32_t l = (uint32_t)p;
    uint32_t b = l / CHUNK;
    uint32_t dst = base_s[b] + (i - excl[b]);
    if (dst < CAP) pairs[(size_t)b * CAP + dst] = p;
  }

  grid.sync();   // #2: pairs + gcount complete everywhere

  // ================= Phase B: dense replay of bucket blk =================
  uint32_t cnt = gcount[blk];
  if (cnt > CAP) cnt = CAP;
  uint32_t ml[8]; float mv[8];
  const uint64_t* bp = pairs + (size_t)blk * CAP;
  const uint32_t cbase = (uint32_t)(blk * CHUNK);
#pragma unroll
  for (int i = 0; i < 8; ++i) {
    uint32_t idx = (uint32_t)tid + (uint32_t)i * 1024u;
    uint64_t p = (idx < cnt) ? bp[idx] : ~0ull;
    ml[i] = (uint32_t)p - cbase;          // sentinel -> huge
    mv[i] = __uint_as_float((uint32_t)(p >> 32));
  }

  float* chunk = (float*)smem;            // 2 halves of SUBF floats
  f32x4* c4 = (f32x4*)chunk;
  const f32x4 z = {0.f, 0.f, 0.f, 0.f};
#pragma unroll
  for (int j = 0; j < 4; ++j) {
    int idx = tid + j * 1024;
    if (idx < (2 * SUBF) / 4) c4[idx] = z;
  }
  __syncthreads();

  // scatter pass 0 into half 0
#pragma unroll
  for (int i = 0; i < 8; ++i)
    if (ml[i] < SUBF) chunk[ml[i]] = mv[i];
  __syncthreads();

  const size_t outbase = (size_t)blk * CHUNK;
  for (int p = 0; p < NSUB; ++p) {
    // scatter next sub-chunk into the other half (overlaps the dump below)
    if (p + 1 < NSUB) {
      uint32_t lo = (uint32_t)((p + 1) * SUBF);
      float* dsth = chunk + ((p + 1) & 1) * SUBF;
#pragma unroll
      for (int i = 0; i < 8; ++i) {
        uint32_t loc = ml[i] - lo;
        if (loc < SUBF) dsth[loc] = mv[i];
      }
    }
    // dump current half dense + rezero
    f32x4* src = (f32x4*)(chunk + (p & 1) * SUBF);
    f32x4* o4  = (f32x4*)(out + outbase + (size_t)p * SUBF);
#pragma unroll
    for (int j = 0; j < 2; ++j) {
      int idx = tid + j * 1024;
      if (idx < SUBF / 4) {
        f32x4 w = src[idx];
        src[idx] = z;                 // rides under the global store
        o4[idx] = w;
      }
    }
    __syncthreads();
  }
}

// ===================== Fallback path (round-2 proven) =====================
__global__ __launch_bounds__(512) void bin_kernel(
    const f32x4* __restrict__ vals,
    const i32x4* __restrict__ nodes,
    const i32x4* __restrict__ feats,
    uint64_t* __restrict__ pairs,
    uint32_t* __restrict__ gcount) {
  __shared__ uint32_t hist[NBUCKET];
  __shared__ uint32_t excl[NBUCKET];
  __shared__ uint32_t base_s[NBUCKET];
  __shared__ uint32_t wpart[8];
  __shared__ uint32_t tot_s;
  __shared__ alignas(16) uint64_t sp[BIN_GPB * 4];
  const int tid = threadIdx.x;
  hist[tid] = 0;
  __syncthreads();

  uint32_t lin[8]; float val[8]; uint32_t rnk[8];
  const int gbase = blockIdx.x * BIN_GPB;
#pragma unroll
  for (int q = 0; q < 2; ++q) {
    int g = gbase + q * 512 + tid;
    bool a = (g < N_GROUPS);
    int gg = a ? g : 0;
    f32x4 v = vals[gg];
    i32x4 n = nodes[gg];
    i32x4 f = feats[gg];
    uint32_t rowbase = (uint32_t)((gg * 4) / D_ELEMS) * (uint32_t)(N_NODES * N_FEATS);
    lin[q*4+0] = a ? rowbase + (uint32_t)n.x * N_FEATS + (uint32_t)f.x : 0xFFFFFFFFu;
    lin[q*4+1] = a ? rowbase + (uint32_t)n.y * N_FEATS + (uint32_t)f.y : 0xFFFFFFFFu;
    lin[q*4+2] = a ? rowbase + (uint32_t)n.z * N_FEATS + (uint32_t)f.z : 0xFFFFFFFFu;
    lin[q*4+3] = a ? rowbase + (uint32_t)n.w * N_FEATS + (uint32_t)f.w : 0xFFFFFFFFu;
    val[q*4+0] = v.x; val[q*4+1] = v.y; val[q*4+2] = v.z; val[q*4+3] = v.w;
  }

#pragma unroll
  for (int i = 0; i < 8; ++i)
    if (lin[i] != 0xFFFFFFFFu)
      rnk[i] = atomicAdd(&hist[lin[i] / CHUNK], 1u);
  __syncthreads();

  uint32_t h = hist[tid];
  uint32_t v = h;
#pragma unroll
  for (int s = 1; s < 64; s <<= 1) {
    uint32_t u = __shfl_up(v, s, 64);
    if ((tid & 63) >= s) v += u;
  }
  if ((tid & 63) == 63) wpart[tid >> 6] = v;
  __syncthreads();
  if (tid < 64) {
    uint32_t p = (tid < 8) ? wpart[tid] : 0u;
#pragma unroll
    for (int s = 1; s < 8; s <<= 1) {
      uint32_t u = __shfl_up(p, s, 64);
      if (tid >= s) p += u;
    }
    if (tid < 8) wpart[tid] = p;
  }
  __syncthreads();
  uint32_t woff = (tid >= 64) ? wpart[(tid >> 6) - 1] : 0u;
  uint32_t incl = v + woff;
  excl[tid] = incl - h;
  base_s[tid] = h ? atomicAdd(&gcount[tid], h) : 0u;
  if (tid == 511) tot_s = incl;
  __syncthreads();

#pragma unroll
  for (int i = 0; i < 8; ++i) {
    if (lin[i] != 0xFFFFFFFFu) {
      uint32_t b = lin[i] / CHUNK;
      sp[excl[b] + rnk[i]] =
          ((uint64_t)__float_as_uint(val[i]) << 32) | (uint64_t)lin[i];
    }
  }
  __syncthreads();

  const uint32_t tot = tot_s;
  for (uint32_t i = tid; i < tot; i += 512u) {
    uint64_t p = sp[i];
    uint32_t l = (uint32_t)p;
    uint32_t b = l / CHUNK;
    uint32_t dst = base_s[b] + (i - excl[b]);
    if (dst < CAP) pairs[(size_t)b * CAP + dst] = p;
  }
}

__global__ __launch_bounds__(1024) void expand_kernel(
    const uint64_t* __restrict__ pairs,
    const uint32_t* __restrict__ gcount,
    float* __restrict__ out) {
  __shared__ alignas(16) float chunk[2 * SUBF];  // 64 KB, double-buffered
  const int b = blockIdx.x;
  const int tid = threadIdx.x;
  uint32_t cnt = gcount[b];
  if (cnt > CAP) cnt = CAP;

  uint32_t ml[8]; float mv[8];
  const uint64_t* bp = pairs + (size_t)b * CAP;
  const uint32_t cbase = (uint32_t)(b * CHUNK);
#pragma unroll
  for (int i = 0; i < 8; ++i) {
    uint32_t idx = (uint32_t)tid + (uint32_t)i * 1024u;
    uint64_t p = (idx < cnt) ? bp[idx] : ~0ull;
    ml[i] = (uint32_t)p - cbase;
    mv[i] = __uint_as_float((uint32_t)(p >> 32));
  }

  f32x4* c4 = (f32x4*)chunk;
  const f32x4 z = {0.f, 0.f, 0.f, 0.f};
#pragma unroll
  for (int j = 0; j < 4; ++j) {
    int idx = tid + j * 1024;
    if (idx < (2 * SUBF) / 4) c4[idx] = z;
  }
  __syncthreads();

#pragma unroll
  for (int i = 0; i < 8; ++i)
    if (ml[i] < SUBF) chunk[ml[i]] = mv[i];
  __syncthreads();

  const size_t outbase = (size_t)b * CHUNK;
  for (int p = 0; p < NSUB; ++p) {
    if (p + 1 < NSUB) {
      uint32_t lo = (uint32_t)((p + 1) * SUBF);
      float* dsth = chunk + ((p + 1) & 1) * SUBF;
#pragma unroll
      for (int i = 0; i < 8; ++i) {
        uint32_t loc = ml[i] - lo;
        if (loc < SUBF) dsth[loc] = mv[i];
      }
    }
    f32x4* src = (f32x4*)(chunk + (p & 1) * SUBF);
    f32x4* o4  = (f32x4*)(out + outbase + (size_t)p * SUBF);
#pragma unroll
    for (int j = 0; j < 2; ++j) {
      int idx = tid + j * 1024;
      if (idx < SUBF / 4) {
        f32x4 w = src[idx];
        src[idx] = z;
        o4[idx] = w;
      }
    }
    __syncthreads();
  }
}

// ---------------- Ultra-fallback (ws too small) ----------------
__global__ __launch_bounds__(256) void scatter4_kernel(
    const f32x4* __restrict__ vals,
    const i32x4* __restrict__ node_ids,
    const i32x4* __restrict__ feat_ids,
    float* __restrict__ out) {
  int t = blockIdx.x * blockDim.x + threadIdx.x;
  if (t >= N_GROUPS) return;
  int b = (t * 4) / D_ELEMS;
  f32x4 v = vals[t];
  i32x4 n = node_ids[t];
  i32x4 f = feat_ids[t];
  size_t base = (size_t)b * N_NODES * N_FEATS;
  out[base + (size_t)n.x * N_FEATS + (size_t)f.x] = v.x;
  out[base + (size_t)n.y * N_FEATS + (size_t)f.y] = v.y;
  out[base + (size_t)n.z * N_FEATS + (size_t)f.z] = v.z;
  out[base + (size_t)n.w * N_FEATS + (size_t)f.w] = v.w;
}

extern "C" void kernel_launch(void* const* d_in, const int* in_sizes, int n_in,
                              void* d_out, int out_size, void* d_ws, size_t ws_size,
                              hipStream_t stream) {
  const f32x4* vals  = (const f32x4*)d_in[0];
  const i32x4* nodes = (const i32x4*)d_in[1];
  const i32x4* feats = (const i32x4*)d_in[2];
  float* out = (float*)d_out;

  const size_t pairs_bytes = (size_t)NBUCKET * CAP * sizeof(uint64_t);  // 33.03 MB
  const size_t need = pairs_bytes + NBUCKET * sizeof(uint32_t);

  if (ws_size >= need) {
    uint64_t* pairs  = (uint64_t*)d_ws;
    uint32_t* gcount = (uint32_t*)((char*)d_ws + pairs_bytes);

    // Preferred: single cooperative dispatch (no memset, no kernel gaps).
    void* kargs[] = {(void*)&vals, (void*)&nodes, (void*)&feats,
                     (void*)&pairs, (void*)&gcount, (void*)&out};
    hipError_t e = hipLaunchCooperativeKernel(
        (void*)fused_kernel, dim3(NBUCKET), dim3(1024), kargs, 0, stream);
    if (e == hipSuccess) return;
    (void)hipGetLastError();   // clear, take the 3-dispatch path

    hipMemsetAsync(gcount, 0, NBUCKET * sizeof(uint32_t), stream);
    bin_kernel<<<BIN_NBLK, 512, 0, stream>>>(vals, nodes, feats, pairs, gcount);
    expand_kernel<<<NBUCKET, 1024, 0, stream>>>(pairs, gcount, out);
  } else {
    hipMemsetAsync(out, 0, (size_t)out_size * sizeof(float), stream);
    const int grid = (N_GROUPS + 255) / 256;  // 3125
    scatter4_kernel<<<grid, 256, 0, stream>>>(vals, nodes, feats, out);
  }
}

// Round 4
// 49.095 us; speedup vs baseline: 2.9288x; 2.9288x over previous
//
#include <hip/hip_runtime.h>
#include <stdint.h>

// Problem constants (from reference)
#define N_NODES 10000
#define N_FEATS 128
#define BSZ 32
#define D_ELEMS 100000

#define OUT_ELEMS (BSZ * N_NODES * N_FEATS)   // 40,960,000 floats
#define N_ITEMS   (BSZ * D_ELEMS)             // 3,200,000
#define N_GROUPS  (N_ITEMS / 4)               // 800,000 x4-groups

#define NBUCKET 512
#define CHUNK   (OUT_ELEMS / NBUCKET)         // 80,000 floats per bucket (exact)
#define CAP     8064                          // mean 6250, sigma~79 -> +23 sigma; 33.03 MB total
#define SUBF    8000                          // floats per LDS half (32 KB); double-buffered
#define NSUB    (CHUNK / SUBF)                // 10 (exact)

// Bin geometry: 512 threads x 8 items = 4096 items/block, staged in 32 KB LDS.
#define BIN_GPB   1024                            // x4-groups per bin block
#define BIN_IPB   (BIN_GPB * 4)                   // 4096 items
#define BIN_NBLK  ((N_GROUPS + BIN_GPB - 1) / BIN_GPB)  // 782

typedef float f32x4 __attribute__((ext_vector_type(4)));
typedef int   i32x4 __attribute__((ext_vector_type(4)));

// ---------------- Phase 1: bin items, block-local sort, run-coalesced flush ----------------
// EXACT round-2 kernel (proven 48.9 us total). Pairs bucket-sorted in LDS,
// flushed so consecutive lanes write consecutive addresses of the same
// bucket run (coalesced ~64B segments).
__global__ __launch_bounds__(512) void bin_kernel(
    const f32x4* __restrict__ vals,
    const i32x4* __restrict__ nodes,
    const i32x4* __restrict__ feats,
    uint64_t* __restrict__ pairs,      // [NBUCKET][CAP]
    uint32_t* __restrict__ gcount) {   // [NBUCKET], pre-zeroed
  __shared__ uint32_t hist[NBUCKET];
  __shared__ uint32_t excl[NBUCKET];
  __shared__ uint32_t base_s[NBUCKET];
  __shared__ uint32_t wpart[8];
  __shared__ uint32_t tot_s;
  __shared__ alignas(16) uint64_t sp[BIN_IPB];   // 32 KB staged pairs
  const int tid = threadIdx.x;
  hist[tid] = 0;
  __syncthreads();

  uint32_t lin[8]; float val[8]; uint32_t rnk[8];
  const int gbase = blockIdx.x * BIN_GPB;
#pragma unroll
  for (int q = 0; q < 2; ++q) {
    int g = gbase + q * 512 + tid;
    bool a = (g < N_GROUPS);
    int gg = a ? g : 0;
    f32x4 v = vals[gg];
    i32x4 n = nodes[gg];
    i32x4 f = feats[gg];
    uint32_t rowbase = (uint32_t)((gg * 4) / D_ELEMS) * (uint32_t)(N_NODES * N_FEATS);
    lin[q*4+0] = a ? rowbase + (uint32_t)n.x * N_FEATS + (uint32_t)f.x : 0xFFFFFFFFu;
    lin[q*4+1] = a ? rowbase + (uint32_t)n.y * N_FEATS + (uint32_t)f.y : 0xFFFFFFFFu;
    lin[q*4+2] = a ? rowbase + (uint32_t)n.z * N_FEATS + (uint32_t)f.z : 0xFFFFFFFFu;
    lin[q*4+3] = a ? rowbase + (uint32_t)n.w * N_FEATS + (uint32_t)f.w : 0xFFFFFFFFu;
    val[q*4+0] = v.x; val[q*4+1] = v.y; val[q*4+2] = v.z; val[q*4+3] = v.w;
  }

#pragma unroll
  for (int i = 0; i < 8; ++i)
    if (lin[i] != 0xFFFFFFFFu)
      rnk[i] = atomicAdd(&hist[lin[i] / CHUNK], 1u);
  __syncthreads();

  // Exclusive scan of the 512-entry hist: wave-level shuffle scan + 8 partials.
  uint32_t h = hist[tid];
  uint32_t v = h;
#pragma unroll
  for (int s = 1; s < 64; s <<= 1) {
    uint32_t u = __shfl_up(v, s, 64);
    if ((tid & 63) >= s) v += u;
  }
  if ((tid & 63) == 63) wpart[tid >> 6] = v;
  __syncthreads();
  if (tid < 64) {
    uint32_t p = (tid < 8) ? wpart[tid] : 0u;
#pragma unroll
    for (int s = 1; s < 8; s <<= 1) {
      uint32_t u = __shfl_up(p, s, 64);
      if (tid >= s) p += u;
    }
    if (tid < 8) wpart[tid] = p;   // inclusive partial sums
  }
  __syncthreads();
  uint32_t woff = (tid >= 64) ? wpart[(tid >> 6) - 1] : 0u;
  uint32_t incl = v + woff;
  excl[tid] = incl - h;
  // per-bucket global base (one atomic per bucket per block)
  base_s[tid] = h ? atomicAdd(&gcount[tid], h) : 0u;
  if (tid == 511) tot_s = incl;
  __syncthreads();

  // stage pairs bucket-sorted in LDS
#pragma unroll
  for (int i = 0; i < 8; ++i) {
    if (lin[i] != 0xFFFFFFFFu) {
      uint32_t b = lin[i] / CHUNK;
      sp[excl[b] + rnk[i]] =
          ((uint64_t)__float_as_uint(val[i]) << 32) | (uint64_t)lin[i];
    }
  }
  __syncthreads();

  // run-coalesced flush
  const uint32_t tot = tot_s;
  for (uint32_t i = tid; i < tot; i += 512u) {
    uint64_t p = sp[i];
    uint32_t l = (uint32_t)p;
    uint32_t b = l / CHUNK;
    uint32_t dst = base_s[b] + (i - excl[b]);
    if (dst < CAP) pairs[(size_t)b * CAP + dst] = p;
  }
}

// ---------------- Phase 2: dense replay, double-buffered ----------------
// Change vs round-2: two 8000-float LDS halves. scatter(p+1) into half B
// overlaps dump+rezero(p) from half A -> the global store stream doesn't
// stall at a barrier between every scatter and dump; one barrier per pass.
// VGPR stays ~48-64 -> still 2 blocks/CU (64 KB LDS each), 32 waves/CU.
__global__ __launch_bounds__(1024) void expand_kernel(
    const uint64_t* __restrict__ pairs,
    const uint32_t* __restrict__ gcount,
    float* __restrict__ out) {
  __shared__ alignas(16) float chunk[2 * SUBF];  // 64 KB
  const int b = blockIdx.x;
  const int tid = threadIdx.x;
  uint32_t cnt = gcount[b];
  if (cnt > CAP) cnt = CAP;

  // Load my share of the bucket's pairs (cnt <= 8064 -> <= 8 per thread).
  uint32_t ml[8];
  float    mv[8];
  const uint64_t* bp = pairs + (size_t)b * CAP;
  const uint32_t cbase = (uint32_t)(b * CHUNK);
#pragma unroll
  for (int i = 0; i < 8; ++i) {
    uint32_t idx = (uint32_t)tid + (uint32_t)i * 1024u;
    uint64_t p = (idx < cnt) ? bp[idx] : ~0ull;
    ml[i] = (uint32_t)p - cbase;          // sentinel -> huge, never < CHUNK
    mv[i] = __uint_as_float((uint32_t)(p >> 32));
  }

  // zero both halves once
  f32x4* c4 = (f32x4*)chunk;
  const f32x4 z = {0.f, 0.f, 0.f, 0.f};
#pragma unroll
  for (int j = 0; j < 4; ++j) {
    int idx = tid + j * 1024;
    if (idx < (2 * SUBF) / 4) c4[idx] = z;
  }
  __syncthreads();

  // scatter pass 0 into half 0
#pragma unroll
  for (int i = 0; i < 8; ++i)
    if (ml[i] < SUBF) chunk[ml[i]] = mv[i];
  __syncthreads();

  const size_t outbase = (size_t)b * CHUNK;
  for (int p = 0; p < NSUB; ++p) {
    // scatter next sub-chunk into the other half (overlaps the dump below)
    if (p + 1 < NSUB) {
      uint32_t lo = (uint32_t)((p + 1) * SUBF);
      float* dsth = chunk + ((p + 1) & 1) * SUBF;
#pragma unroll
      for (int i = 0; i < 8; ++i) {
        uint32_t loc = ml[i] - lo;
        if (loc < SUBF) dsth[loc] = mv[i];
      }
    }
    // dump current half dense + rezero (rezero rides under the global store)
    f32x4* src = (f32x4*)(chunk + (p & 1) * SUBF);
    f32x4* o4  = (f32x4*)(out + outbase + (size_t)p * SUBF);
#pragma unroll
    for (int j = 0; j < 2; ++j) {
      int idx = tid + j * 1024;
      if (idx < SUBF / 4) {
        f32x4 w = src[idx];
        src[idx] = z;
        o4[idx] = w;
      }
    }
    __syncthreads();  // half rezeroed + dumped; other half fully scattered
  }
}

// ---------------- Fallback (ws too small): memset + plain scatter ----------------
__global__ __launch_bounds__(256) void scatter4_kernel(
    const f32x4* __restrict__ vals,
    const i32x4* __restrict__ node_ids,
    const i32x4* __restrict__ feat_ids,
    float* __restrict__ out) {
  int t = blockIdx.x * blockDim.x + threadIdx.x;
  if (t >= N_GROUPS) return;
  int b = (t * 4) / D_ELEMS;
  f32x4 v = vals[t];
  i32x4 n = node_ids[t];
  i32x4 f = feat_ids[t];
  size_t base = (size_t)b * N_NODES * N_FEATS;
  out[base + (size_t)n.x * N_FEATS + (size_t)f.x] = v.x;
  out[base + (size_t)n.y * N_FEATS + (size_t)f.y] = v.y;
  out[base + (size_t)n.z * N_FEATS + (size_t)f.z] = v.z;
  out[base + (size_t)n.w * N_FEATS + (size_t)f.w] = v.w;
}

extern "C" void kernel_launch(void* const* d_in, const int* in_sizes, int n_in,
                              void* d_out, int out_size, void* d_ws, size_t ws_size,
                              hipStream_t stream) {
  const float* vals     = (const float*)d_in[0];
  const int*   node_ids = (const int*)d_in[1];
  const int*   feat_ids = (const int*)d_in[2];
  float* out = (float*)d_out;

  const size_t pairs_bytes = (size_t)NBUCKET * CAP * sizeof(uint64_t);  // 33.03 MB
  const size_t need = pairs_bytes + NBUCKET * sizeof(uint32_t);

  if (ws_size >= need) {
    uint64_t* pairs  = (uint64_t*)d_ws;
    uint32_t* gcount = (uint32_t*)((char*)d_ws + pairs_bytes);
    hipMemsetAsync(gcount, 0, NBUCKET * sizeof(uint32_t), stream);
    bin_kernel<<<BIN_NBLK, 512, 0, stream>>>(
        (const f32x4*)vals, (const i32x4*)node_ids, (const i32x4*)feat_ids,
        pairs, gcount);
    expand_kernel<<<NBUCKET, 1024, 0, stream>>>(pairs, gcount, out);
  } else {
    hipMemsetAsync(out, 0, (size_t)out_size * sizeof(float), stream);
    const int grid = (N_GROUPS + 255) / 256;  // 3125
    scatter4_kernel<<<grid, 256, 0, stream>>>(
        (const f32x4*)vals, (const i32x4*)node_ids, (const i32x4*)feat_ids, out);
  }
}